// Round 1
// baseline (326.205 us; speedup 1.0000x reference)
//
#include <hip/hip_runtime.h>

#define SEQ 4096
#define DM  1024
#define DH  64
#define NB  4

typedef __attribute__((ext_vector_type(4))) float  f32x4;
typedef __attribute__((ext_vector_type(8))) __bf16 bf16x8;

__device__ __forceinline__ unsigned short f2bf(float f) {
    unsigned int u = __float_as_uint(f);
    u += 0x7FFFu + ((u >> 16) & 1u);          // RNE
    return (unsigned short)(u >> 16);
}

__device__ __forceinline__ f32x4 mfma_bf16(bf16x8 a, bf16x8 b, f32x4 c) {
    return __builtin_amdgcn_mfma_f32_16x16x32_bf16(a, b, c, 0, 0, 0);
}

// ---------------------------------------------------------------------------
// Projection: Y = X[16384,1024] @ W[64,1024]^T + b  -> bf16
//   which=0: qh [B*S][64]; which=1: kh [B*S][64]; which=2: vhT [B][64][S]
// ---------------------------------------------------------------------------
__global__ __launch_bounds__(256) void proj_kernel(
    const float* __restrict__ xq, const float* __restrict__ xk, const float* __restrict__ xv,
    const float* __restrict__ Wq, const float* __restrict__ bq,
    const float* __restrict__ Wk, const float* __restrict__ bk,
    const float* __restrict__ Wv, const float* __restrict__ bv,
    unsigned short* __restrict__ qh, unsigned short* __restrict__ kh,
    unsigned short* __restrict__ vhT)
{
    __shared__ unsigned short x_tile[64][72];   // pad 72: b128 frag reads = free 2-way
    __shared__ unsigned short w_tile[64][72];

    const int which = blockIdx.y;
    const float* X  = (which == 0) ? xq : (which == 1) ? xk : xv;
    const float* W  = (which == 0) ? Wq : (which == 1) ? Wk : Wv;
    const float* Bb = (which == 0) ? bq : (which == 1) ? bk : bv;

    const int m0   = blockIdx.x * 64;
    const int t    = threadIdx.x;
    const int wv   = t >> 6;
    const int lane = t & 63;
    const int quad = lane >> 4;
    const int l16  = lane & 15;
    const int sr   = t >> 2;           // staging row 0..63
    const int sc   = (t & 3) << 4;     // staging col chunk {0,16,32,48}

    f32x4 acc[4];
#pragma unroll
    for (int i = 0; i < 4; ++i) acc[i] = f32x4{0.f, 0.f, 0.f, 0.f};

    for (int kc = 0; kc < DM; kc += 64) {
        __syncthreads();
        const float* xg = X + (size_t)(m0 + sr) * DM + (kc + sc);
        const float* wg = W + (size_t)sr * DM + (kc + sc);
#pragma unroll
        for (int i = 0; i < 4; ++i) {
            f32x4 xvv = *(const f32x4*)(xg + i * 4);
            f32x4 wvv = *(const f32x4*)(wg + i * 4);
            ushort4 xs = make_ushort4(f2bf(xvv[0]), f2bf(xvv[1]), f2bf(xvv[2]), f2bf(xvv[3]));
            ushort4 ws = make_ushort4(f2bf(wvv[0]), f2bf(wvv[1]), f2bf(wvv[2]), f2bf(wvv[3]));
            *(ushort4*)&x_tile[sr][sc + i * 4] = xs;
            *(ushort4*)&w_tile[sr][sc + i * 4] = ws;
        }
        __syncthreads();
#pragma unroll
        for (int ks = 0; ks < 2; ++ks) {
            bf16x8 a = *(const bf16x8*)&x_tile[wv * 16 + l16][ks * 32 + quad * 8];
#pragma unroll
            for (int nt = 0; nt < 4; ++nt) {
                bf16x8 b = *(const bf16x8*)&w_tile[nt * 16 + l16][ks * 32 + quad * 8];
                acc[nt] = mfma_bf16(a, b, acc[nt]);
            }
        }
    }

    __syncthreads();
    // C-layout (col=l16, row=quad*4+r) + bias -> bf16 into x_tile for coalesced store
#pragma unroll
    for (int nt = 0; nt < 4; ++nt) {
        float bias = Bb[nt * 16 + l16];
#pragma unroll
        for (int r = 0; r < 4; ++r)
            x_tile[wv * 16 + quad * 4 + r][nt * 16 + l16] = f2bf(acc[nt][r] + bias);
    }
    __syncthreads();

    if (which < 2) {
        unsigned short* out = (which == 0) ? qh : kh;
        unsigned short* og  = out + (size_t)(m0 + sr) * DH + sc;
        *(int4*)og       = *(const int4*)&x_tile[sr][sc];
        *(int4*)(og + 8) = *(const int4*)&x_tile[sr][sc + 8];
    } else {
        // store transposed: vhT[b][h][s]
        const int bb = m0 >> 12;        // m0 / 4096
        const int s0 = m0 & 4095;
        const int h  = sr;
        const int r0 = sc;
        __align__(16) unsigned short tmp[16];
#pragma unroll
        for (int i = 0; i < 16; ++i) tmp[i] = x_tile[r0 + i][h];
        unsigned short* og = vhT + (size_t)bb * DH * SEQ + (size_t)h * SEQ + (s0 + r0);
        *(int4*)og       = *(const int4*)&tmp[0];
        *(int4*)(og + 8) = *(const int4*)&tmp[8];
    }
}

// ---------------------------------------------------------------------------
// Flash attention, causal. 1 block = 64 q-rows (4 waves x 16 rows).
// ---------------------------------------------------------------------------
__global__ __launch_bounds__(256) void attn_kernel(
    const unsigned short* __restrict__ qh, const unsigned short* __restrict__ kh,
    const unsigned short* __restrict__ vhT, float* __restrict__ out)
{
    __shared__ unsigned short k_t[64][72];   // K tile [key][h]
    __shared__ unsigned short v_t[64][72];   // V^T tile [h][key]
    __shared__ unsigned short qp[64][72];    // Q tile, then P tile [row][key]

    const int qt   = blockIdx.x;
    const int b    = blockIdx.y;
    const int t    = threadIdx.x;
    const int wv   = t >> 6;
    const int lane = t & 63;
    const int quad = lane >> 4;
    const int l16  = lane & 15;
    const int sr   = t >> 2;
    const int sc   = (t & 3) << 4;

    const size_t base = (size_t)b * SEQ * DH;

    {   // stage Q tile
        const unsigned short* g = qh + base + (size_t)(qt * 64 + sr) * DH + sc;
        *(int4*)&qp[sr][sc]     = *(const int4*)g;
        *(int4*)&qp[sr][sc + 8] = *(const int4*)(g + 8);
    }
    __syncthreads();
    bf16x8 qfrag[2];
    qfrag[0] = *(const bf16x8*)&qp[wv * 16 + l16][quad * 8];
    qfrag[1] = *(const bf16x8*)&qp[wv * 16 + l16][32 + quad * 8];
    // qp rows are wave-private from here on (wave w owns rows [16w,16w+16))

    f32x4 o_acc[4];
#pragma unroll
    for (int i = 0; i < 4; ++i) o_acc[i] = f32x4{0.f, 0.f, 0.f, 0.f};
    float m_i[4], l_i[4];
#pragma unroll
    for (int r = 0; r < 4; ++r) { m_i[r] = -1e30f; l_i[r] = 0.f; }

    const int rowb = wv * 16 + quad * 4;

    for (int jt = 0; jt <= qt; ++jt) {
        __syncthreads();   // all waves done reading k_t/v_t of previous tile
        {
            const unsigned short* kg = kh + base + (size_t)(jt * 64 + sr) * DH + sc;
            *(int4*)&k_t[sr][sc]     = *(const int4*)kg;
            *(int4*)&k_t[sr][sc + 8] = *(const int4*)(kg + 8);
            const unsigned short* vg = vhT + (size_t)b * DH * SEQ + (size_t)sr * SEQ + (jt * 64 + sc);
            *(int4*)&v_t[sr][sc]     = *(const int4*)vg;
            *(int4*)&v_t[sr][sc + 8] = *(const int4*)(vg + 8);
        }
        __syncthreads();

        // S = Q K^T  (16 rows x 64 keys per wave)
        f32x4 s_acc[4];
#pragma unroll
        for (int i = 0; i < 4; ++i) s_acc[i] = f32x4{0.f, 0.f, 0.f, 0.f};
#pragma unroll
        for (int ks = 0; ks < 2; ++ks) {
#pragma unroll
            for (int nt = 0; nt < 4; ++nt) {
                bf16x8 bfr = *(const bf16x8*)&k_t[nt * 16 + l16][ks * 32 + quad * 8];
                s_acc[nt] = mfma_bf16(qfrag[ks], bfr, s_acc[nt]);
            }
        }

        // scale + causal mask (diagonal tile only)
        const bool diag = (jt == qt);
#pragma unroll
        for (int nt = 0; nt < 4; ++nt) {
            const int col = nt * 16 + l16;
#pragma unroll
            for (int r = 0; r < 4; ++r) {
                float sv = s_acc[nt][r] * 0.125f;
                if (diag && (col > rowb + r)) sv = -1e30f;
                s_acc[nt][r] = sv;
            }
        }

        // row max across 64 keys: 4 frags then 16-lane butterfly (stays in quad)
        float mx[4];
#pragma unroll
        for (int r = 0; r < 4; ++r)
            mx[r] = fmaxf(fmaxf(s_acc[0][r], s_acc[1][r]), fmaxf(s_acc[2][r], s_acc[3][r]));
#pragma unroll
        for (int off = 1; off < 16; off <<= 1)
#pragma unroll
            for (int r = 0; r < 4; ++r)
                mx[r] = fmaxf(mx[r], __shfl_xor(mx[r], off, 64));

        float alpha[4];
#pragma unroll
        for (int r = 0; r < 4; ++r) {
            float mn = fmaxf(m_i[r], mx[r]);
            alpha[r] = __expf(m_i[r] - mn);
            m_i[r]   = mn;
        }

        float rs[4] = {0.f, 0.f, 0.f, 0.f};
#pragma unroll
        for (int nt = 0; nt < 4; ++nt)
#pragma unroll
            for (int r = 0; r < 4; ++r) {
                float p = __expf(s_acc[nt][r] - m_i[r]);
                s_acc[nt][r] = p;
                rs[r] += p;
            }
#pragma unroll
        for (int off = 1; off < 16; off <<= 1)
#pragma unroll
            for (int r = 0; r < 4; ++r)
                rs[r] += __shfl_xor(rs[r], off, 64);
#pragma unroll
        for (int r = 0; r < 4; ++r) l_i[r] = l_i[r] * alpha[r] + rs[r];

        // P -> LDS (bf16), wave-private rows; then O = alpha*O + P V
#pragma unroll
        for (int nt = 0; nt < 4; ++nt)
#pragma unroll
            for (int r = 0; r < 4; ++r)
                qp[rowb + r][nt * 16 + l16] = f2bf(s_acc[nt][r]);

#pragma unroll
        for (int nt = 0; nt < 4; ++nt)
#pragma unroll
            for (int r = 0; r < 4; ++r)
                o_acc[nt][r] *= alpha[r];

#pragma unroll
        for (int ks = 0; ks < 2; ++ks) {
            bf16x8 pa = *(const bf16x8*)&qp[wv * 16 + l16][ks * 32 + quad * 8];
#pragma unroll
            for (int nt = 0; nt < 4; ++nt) {
                bf16x8 vb = *(const bf16x8*)&v_t[nt * 16 + l16][ks * 32 + quad * 8];
                o_acc[nt] = mfma_bf16(pa, vb, o_acc[nt]);
            }
        }
    }

    float inv[4];
#pragma unroll
    for (int r = 0; r < 4; ++r) inv[r] = 1.0f / l_i[r];
#pragma unroll
    for (int nt = 0; nt < 4; ++nt)
#pragma unroll
        for (int r = 0; r < 4; ++r)
            out[base + (size_t)(qt * 64 + rowb + r) * DH + nt * 16 + l16] = o_acc[nt][r] * inv[r];
}

extern "C" void kernel_launch(void* const* d_in, const int* in_sizes, int n_in,
                              void* d_out, int out_size, void* d_ws, size_t ws_size,
                              hipStream_t stream)
{
    (void)in_sizes; (void)n_in; (void)out_size; (void)ws_size;
    const float* q  = (const float*)d_in[0];
    const float* k  = (const float*)d_in[1];
    const float* v  = (const float*)d_in[2];
    const float* Wq = (const float*)d_in[3];
    const float* bq = (const float*)d_in[4];
    const float* Wk = (const float*)d_in[5];
    const float* bk = (const float*)d_in[6];
    const float* Wv = (const float*)d_in[7];
    const float* bv = (const float*)d_in[8];
    float* out = (float*)d_out;

    unsigned short* qh  = (unsigned short*)d_ws;
    unsigned short* kh  = qh + (size_t)NB * SEQ * DH;
    unsigned short* vhT = kh + (size_t)NB * SEQ * DH;

    proj_kernel<<<dim3(NB * SEQ / 64, 3), 256, 0, stream>>>(
        q, k, v, Wq, bq, Wk, bk, Wv, bv, qh, kh, vhT);
    attn_kernel<<<dim3(SEQ / 64, NB), 256, 0, stream>>>(qh, kh, vhT, out);
}

// Round 2
// 281.264 us; speedup vs baseline: 1.1598x; 1.1598x over previous
//
#include <hip/hip_runtime.h>

#define SEQ 4096
#define DM  1024
#define DH  64
#define NB  4
#define SLOTS_PER_B 288   // sum_{qt=0}^{63} ceil((qt+1)/8)

typedef __attribute__((ext_vector_type(4))) float  f32x4;
typedef __attribute__((ext_vector_type(8))) __bf16 bf16x8;

__device__ __forceinline__ unsigned short f2bf(float f) {
    unsigned int u = __float_as_uint(f);
    u += 0x7FFFu + ((u >> 16) & 1u);          // RNE
    return (unsigned short)(u >> 16);
}

__device__ __forceinline__ f32x4 mfma_bf16(bf16x8 a, bf16x8 b, f32x4 c) {
    return __builtin_amdgcn_mfma_f32_16x16x32_bf16(a, b, c, 0, 0, 0);
}

// ---------------------------------------------------------------------------
// Projection: Y = X[16384,1024] @ W[64,1024]^T + b  -> bf16
//   which=0: qh [B*S][64]; which=1: kh [B*S][64]; which=2: vhT [B][64][S]
// Software-pipelined: next K-chunk prefetched to registers across the barrier.
// ---------------------------------------------------------------------------
__global__ __launch_bounds__(256) void proj_kernel(
    const float* __restrict__ xq, const float* __restrict__ xk, const float* __restrict__ xv,
    const float* __restrict__ Wq, const float* __restrict__ bq,
    const float* __restrict__ Wk, const float* __restrict__ bk,
    const float* __restrict__ Wv, const float* __restrict__ bv,
    unsigned short* __restrict__ qh, unsigned short* __restrict__ kh,
    unsigned short* __restrict__ vhT)
{
    __shared__ unsigned short x_tile[64][72];   // pad 72: b128 frag reads = free 2-way
    __shared__ unsigned short w_tile[64][72];

    const int which = blockIdx.y;
    const float* X  = (which == 0) ? xq : (which == 1) ? xk : xv;
    const float* W  = (which == 0) ? Wq : (which == 1) ? Wk : Wv;
    const float* Bb = (which == 0) ? bq : (which == 1) ? bk : bv;

    const int m0   = blockIdx.x * 64;
    const int t    = threadIdx.x;
    const int wv   = t >> 6;
    const int lane = t & 63;
    const int quad = lane >> 4;
    const int l16  = lane & 15;
    const int sr   = t >> 2;           // staging row 0..63
    const int sc   = (t & 3) << 4;     // staging col chunk {0,16,32,48}

    f32x4 acc[4];
#pragma unroll
    for (int i = 0; i < 4; ++i) acc[i] = f32x4{0.f, 0.f, 0.f, 0.f};

    const float* xg = X + (size_t)(m0 + sr) * DM + sc;
    const float* wg = W + (size_t)sr * DM + sc;

    f32x4 xr[4], wr[4];
#pragma unroll
    for (int i = 0; i < 4; ++i) { xr[i] = *(const f32x4*)(xg + i * 4); wr[i] = *(const f32x4*)(wg + i * 4); }

    for (int kc = 0; kc < DM; kc += 64) {
        __syncthreads();   // previous iteration's MFMA reads done
#pragma unroll
        for (int i = 0; i < 4; ++i) {
            *(ushort4*)&x_tile[sr][sc + i * 4] =
                make_ushort4(f2bf(xr[i][0]), f2bf(xr[i][1]), f2bf(xr[i][2]), f2bf(xr[i][3]));
            *(ushort4*)&w_tile[sr][sc + i * 4] =
                make_ushort4(f2bf(wr[i][0]), f2bf(wr[i][1]), f2bf(wr[i][2]), f2bf(wr[i][3]));
        }
        __syncthreads();
        if (kc + 64 < DM) {   // prefetch next chunk while MFMAs run
            const float* xn = xg + kc + 64;
            const float* wn = wg + kc + 64;
#pragma unroll
            for (int i = 0; i < 4; ++i) { xr[i] = *(const f32x4*)(xn + i * 4); wr[i] = *(const f32x4*)(wn + i * 4); }
        }
#pragma unroll
        for (int ks = 0; ks < 2; ++ks) {
            bf16x8 a = *(const bf16x8*)&x_tile[wv * 16 + l16][ks * 32 + quad * 8];
#pragma unroll
            for (int nt = 0; nt < 4; ++nt) {
                bf16x8 b = *(const bf16x8*)&w_tile[nt * 16 + l16][ks * 32 + quad * 8];
                acc[nt] = mfma_bf16(a, b, acc[nt]);
            }
        }
    }

    __syncthreads();
#pragma unroll
    for (int nt = 0; nt < 4; ++nt) {
        float bias = Bb[nt * 16 + l16];
#pragma unroll
        for (int r = 0; r < 4; ++r)
            x_tile[wv * 16 + quad * 4 + r][nt * 16 + l16] = f2bf(acc[nt][r] + bias);
    }
    __syncthreads();

    if (which < 2) {
        unsigned short* out = (which == 0) ? qh : kh;
        unsigned short* og  = out + (size_t)(m0 + sr) * DH + sc;
        *(int4*)og       = *(const int4*)&x_tile[sr][sc];
        *(int4*)(og + 8) = *(const int4*)&x_tile[sr][sc + 8];
    } else {
        const int bb = m0 >> 12;
        const int s0 = m0 & 4095;
        const int h  = sr;
        const int r0 = sc;
        __align__(16) unsigned short tmp[16];
#pragma unroll
        for (int i = 0; i < 16; ++i) tmp[i] = x_tile[r0 + i][h];
        unsigned short* og = vhT + (size_t)bb * DH * SEQ + (size_t)h * SEQ + (s0 + r0);
        *(int4*)og       = *(const int4*)&tmp[0];
        *(int4*)(og + 8) = *(const int4*)&tmp[8];
    }
}

// ---------------------------------------------------------------------------
// Flash attention, causal, SPLIT-K over key chunks of 8 tiles (512 keys).
// Block (chunk, qt, b) -> partial unnormalized O + (m, l) per row into ws.
// slot = b*288 + off(qt) + chunk, off(qt) = 4g(g+1) + r(g+1), g=qt>>3, r=qt&7.
// ---------------------------------------------------------------------------
__global__ __launch_bounds__(256) void attn_split_kernel(
    const unsigned short* __restrict__ qh, const unsigned short* __restrict__ kh,
    const unsigned short* __restrict__ vhT,
    float* __restrict__ pO, float* __restrict__ pm, float* __restrict__ pl)
{
    const int chunk = blockIdx.x;
    const int qt    = blockIdx.y;
    const int b     = blockIdx.z;
    const int nc    = (qt + 8) >> 3;
    if (chunk >= nc) return;

    const int g = qt >> 3, rr = qt & 7;
    const int slot = b * SLOTS_PER_B + 4 * g * (g + 1) + rr * (g + 1) + chunk;
    const int c0 = chunk * 8;
    const int c1 = min(c0 + 8, qt + 1);

    __shared__ unsigned short k_t[64][72];
    __shared__ unsigned short v_t[64][72];
    __shared__ unsigned short qp[64][72];

    const int t    = threadIdx.x;
    const int wv   = t >> 6;
    const int lane = t & 63;
    const int quad = lane >> 4;
    const int l16  = lane & 15;
    const int sr   = t >> 2;
    const int sc   = (t & 3) << 4;

    const size_t base = (size_t)b * SEQ * DH;

    {   // stage Q tile
        const unsigned short* gq = qh + base + (size_t)(qt * 64 + sr) * DH + sc;
        *(int4*)&qp[sr][sc]     = *(const int4*)gq;
        *(int4*)&qp[sr][sc + 8] = *(const int4*)(gq + 8);
    }
    __syncthreads();
    bf16x8 qfrag[2];
    qfrag[0] = *(const bf16x8*)&qp[wv * 16 + l16][quad * 8];
    qfrag[1] = *(const bf16x8*)&qp[wv * 16 + l16][32 + quad * 8];

    f32x4 o_acc[4];
#pragma unroll
    for (int i = 0; i < 4; ++i) o_acc[i] = f32x4{0.f, 0.f, 0.f, 0.f};
    float m_i[4], l_i[4];
#pragma unroll
    for (int r = 0; r < 4; ++r) { m_i[r] = -1e30f; l_i[r] = 0.f; }

    const int rowb = wv * 16 + quad * 4;

    for (int jt = c0; jt < c1; ++jt) {
        __syncthreads();
        {
            const unsigned short* kg = kh + base + (size_t)(jt * 64 + sr) * DH + sc;
            *(int4*)&k_t[sr][sc]     = *(const int4*)kg;
            *(int4*)&k_t[sr][sc + 8] = *(const int4*)(kg + 8);
            const unsigned short* vg = vhT + (size_t)b * DH * SEQ + (size_t)sr * SEQ + (jt * 64 + sc);
            *(int4*)&v_t[sr][sc]     = *(const int4*)vg;
            *(int4*)&v_t[sr][sc + 8] = *(const int4*)(vg + 8);
        }
        __syncthreads();

        f32x4 s_acc[4];
#pragma unroll
        for (int i = 0; i < 4; ++i) s_acc[i] = f32x4{0.f, 0.f, 0.f, 0.f};
#pragma unroll
        for (int ks = 0; ks < 2; ++ks) {
#pragma unroll
            for (int nt = 0; nt < 4; ++nt) {
                bf16x8 bfr = *(const bf16x8*)&k_t[nt * 16 + l16][ks * 32 + quad * 8];
                s_acc[nt] = mfma_bf16(qfrag[ks], bfr, s_acc[nt]);
            }
        }

        const bool diag = (jt == qt);
#pragma unroll
        for (int nt = 0; nt < 4; ++nt) {
            const int col = nt * 16 + l16;
#pragma unroll
            for (int r = 0; r < 4; ++r) {
                float sv = s_acc[nt][r] * 0.125f;
                if (diag && (col > rowb + r)) sv = -1e30f;
                s_acc[nt][r] = sv;
            }
        }

        float mx[4];
#pragma unroll
        for (int r = 0; r < 4; ++r)
            mx[r] = fmaxf(fmaxf(s_acc[0][r], s_acc[1][r]), fmaxf(s_acc[2][r], s_acc[3][r]));
#pragma unroll
        for (int off = 1; off < 16; off <<= 1)
#pragma unroll
            for (int r = 0; r < 4; ++r)
                mx[r] = fmaxf(mx[r], __shfl_xor(mx[r], off, 64));

        float alpha[4];
#pragma unroll
        for (int r = 0; r < 4; ++r) {
            float mn = fmaxf(m_i[r], mx[r]);
            alpha[r] = __expf(m_i[r] - mn);
            m_i[r]   = mn;
        }

        float rs[4] = {0.f, 0.f, 0.f, 0.f};
#pragma unroll
        for (int nt = 0; nt < 4; ++nt)
#pragma unroll
            for (int r = 0; r < 4; ++r) {
                float p = __expf(s_acc[nt][r] - m_i[r]);
                s_acc[nt][r] = p;
                rs[r] += p;
            }
#pragma unroll
        for (int off = 1; off < 16; off <<= 1)
#pragma unroll
            for (int r = 0; r < 4; ++r)
                rs[r] += __shfl_xor(rs[r], off, 64);
#pragma unroll
        for (int r = 0; r < 4; ++r) l_i[r] = l_i[r] * alpha[r] + rs[r];

#pragma unroll
        for (int nt = 0; nt < 4; ++nt)
#pragma unroll
            for (int r = 0; r < 4; ++r)
                qp[rowb + r][nt * 16 + l16] = f2bf(s_acc[nt][r]);

#pragma unroll
        for (int nt = 0; nt < 4; ++nt)
#pragma unroll
            for (int r = 0; r < 4; ++r)
                o_acc[nt][r] *= alpha[r];

#pragma unroll
        for (int ks = 0; ks < 2; ++ks) {
            bf16x8 pa = *(const bf16x8*)&qp[wv * 16 + l16][ks * 32 + quad * 8];
#pragma unroll
            for (int nt = 0; nt < 4; ++nt) {
                bf16x8 vb = *(const bf16x8*)&v_t[nt * 16 + l16][ks * 32 + quad * 8];
                o_acc[nt] = mfma_bf16(pa, vb, o_acc[nt]);
            }
        }
    }

    // write unnormalized partials
    float* po = pO + (size_t)slot * 4096;
#pragma unroll
    for (int nt = 0; nt < 4; ++nt)
#pragma unroll
        for (int r = 0; r < 4; ++r)
            po[(rowb + r) * 64 + nt * 16 + l16] = o_acc[nt][r];
    if (l16 == 0) {
#pragma unroll
        for (int r = 0; r < 4; ++r) {
            pm[slot * 64 + rowb + r] = m_i[r];
            pl[slot * 64 + rowb + r] = l_i[r];
        }
    }
}

// ---------------------------------------------------------------------------
// Merge partials: out = sum_c exp(m_c - m*) O_c / sum_c exp(m_c - m*) l_c
// Block (qt, b), 256 threads: thread -> (row = t>>2, 16 cols).
// ---------------------------------------------------------------------------
__global__ __launch_bounds__(256) void attn_merge_kernel(
    const float* __restrict__ pO, const float* __restrict__ pm, const float* __restrict__ pl,
    float* __restrict__ out)
{
    const int qt = blockIdx.x;
    const int b  = blockIdx.y;
    const int nc = (qt + 8) >> 3;
    const int g = qt >> 3, rr = qt & 7;
    const int s0 = b * SLOTS_PER_B + 4 * g * (g + 1) + rr * (g + 1);

    const int t   = threadIdx.x;
    const int row = t >> 2;
    const int c0  = (t & 3) << 4;

    float mstar = -1e30f;
    for (int c = 0; c < nc; ++c)
        mstar = fmaxf(mstar, pm[(s0 + c) * 64 + row]);

    f32x4 acc[4];
#pragma unroll
    for (int i = 0; i < 4; ++i) acc[i] = f32x4{0.f, 0.f, 0.f, 0.f};
    float lsum = 0.f;

    for (int c = 0; c < nc; ++c) {
        const float w = __expf(pm[(s0 + c) * 64 + row] - mstar);
        lsum += w * pl[(s0 + c) * 64 + row];
        const float* p = pO + (size_t)(s0 + c) * 4096 + row * 64 + c0;
#pragma unroll
        for (int i = 0; i < 4; ++i) {
            f32x4 v = *(const f32x4*)(p + i * 4);
            acc[i] += w * v;
        }
    }

    const float inv = 1.0f / lsum;
    float* og = out + (size_t)b * SEQ * DH + (size_t)(qt * 64 + row) * DH + c0;
#pragma unroll
    for (int i = 0; i < 4; ++i)
        *(f32x4*)(og + i * 4) = acc[i] * inv;
}

extern "C" void kernel_launch(void* const* d_in, const int* in_sizes, int n_in,
                              void* d_out, int out_size, void* d_ws, size_t ws_size,
                              hipStream_t stream)
{
    (void)in_sizes; (void)n_in; (void)out_size; (void)ws_size;
    const float* q  = (const float*)d_in[0];
    const float* k  = (const float*)d_in[1];
    const float* v  = (const float*)d_in[2];
    const float* Wq = (const float*)d_in[3];
    const float* bq = (const float*)d_in[4];
    const float* Wk = (const float*)d_in[5];
    const float* bk = (const float*)d_in[6];
    const float* Wv = (const float*)d_in[7];
    const float* bv = (const float*)d_in[8];
    float* out = (float*)d_out;

    unsigned short* qh  = (unsigned short*)d_ws;
    unsigned short* kh  = qh + (size_t)NB * SEQ * DH;
    unsigned short* vhT = kh + (size_t)NB * SEQ * DH;
    float* pO = (float*)(vhT + (size_t)NB * SEQ * DH);
    float* pm = pO + (size_t)NB * SLOTS_PER_B * 4096;
    float* pl = pm + (size_t)NB * SLOTS_PER_B * 64;

    proj_kernel<<<dim3(NB * SEQ / 64, 3), 256, 0, stream>>>(
        q, k, v, Wq, bq, Wk, bk, Wv, bv, qh, kh, vhT);
    attn_split_kernel<<<dim3(8, SEQ / 64, NB), 256, 0, stream>>>(qh, kh, vhT, pO, pm, pl);
    attn_merge_kernel<<<dim3(SEQ / 64, NB), 256, 0, stream>>>(pO, pm, pl, out);
}